// Round 3
// baseline (5542.813 us; speedup 1.0000x reference)
//
#include <hip/hip_runtime.h>
#include <hip/hip_fp16.h>
#include <cstdint>

#define B_   128
#define T_   2048
#define DIN  5
#define H_   128
#define G3   384
#define D1   256
#define CH   128
#define NCH  (T_ / CH)

typedef _Float16 half8 __attribute__((ext_vector_type(8)));
typedef float f32x4 __attribute__((ext_vector_type(4)));

__device__ __forceinline__ float sigmoid_f(float x) {
    return 1.0f / (1.0f + __expf(-x));
}
__device__ __forceinline__ float tanh_f(float x) {
    return 1.0f - 2.0f / (__expf(2.0f * x) + 1.0f);
}
__device__ __forceinline__ unsigned long long pack4h(const float* h) {
    union { __half2 h2[2]; unsigned long long u; } pk;
    pk.h2[0] = __floats2half2_rn(h[0], h[1]);
    pk.h2[1] = __floats2half2_rn(h[2], h[3]);
    return pk.u;
}

// ---------------------------------------------------------------------------
// scan0: layer-0 GRU, MFMA-based. One block per (dir, batch-group-of-16).
// 256 threads = 4 waves; wave w owns hidden-tiles {2w, 2w+1}.
// Per step: D(gates x batches) = A(W~ in regs) * B([h|x|1] in LDS, f16).
// A layout: lane l holds row (l&15), k = 32c + (l>>4)*8 + j.
// B layout: lane l holds col (l&15), same k.  D: col=l&15, row=(l>>4)*4+q.
// K = 160: [h(128) | x(5) | 1 | pad].  LDS h-buffer double-buffered,
// row stride 512B, XOR swizzle koff ^ ((batch&7)<<4).  1 barrier/step.
// ---------------------------------------------------------------------------
__global__ __launch_bounds__(256, 2) void scan0_mfma(
    const float* __restrict__ seq,
    const float* __restrict__ wihf, const float* __restrict__ whhf,
    const float* __restrict__ bihf, const float* __restrict__ bhhf,
    const float* __restrict__ wihb, const float* __restrict__ whhb,
    const float* __restrict__ bihb, const float* __restrict__ bhhb,
    __half* __restrict__ y0)
{
    const int tid = threadIdx.x;
    const int w = tid >> 6;          // wave 0..3
    const int l = tid & 63;
    const int lo = l & 15;           // batch lane
    const int g  = l >> 4;           // k-group
    const int dir = blockIdx.x >> 3;
    const int bg  = blockIdx.x & 7;

    const float* w_ih = dir ? wihb : wihf;
    const float* w_hh = dir ? whhb : whhf;
    const float* b_ih = dir ? bihb : bihf;
    const float* b_hh = dir ? bhhb : bhhf;

    __shared__ __align__(16) char smem[2 * 16 * 512];   // 2 buffers x 16 rows x 512B

    // ---- A fragments (weights) into registers ----
    half8 a_r[2][5], a_z[2][5], a_n[2][5], a_x[2];
#pragma unroll
    for (int i = 0; i < 2; ++i) {
        const int grow = (2 * w + i) * 16 + lo;   // r-gate row 0..127
#pragma unroll
        for (int c = 0; c < 5; ++c) {
            half8 vr, vz, vn;
#pragma unroll
            for (int j = 0; j < 8; ++j) {
                const int k = c * 32 + g * 8 + j;
                float fr, fz, fn;
                if (k < 128) {
                    fr = w_hh[grow * H_ + k];
                    fz = w_hh[(128 + grow) * H_ + k];
                    fn = w_hh[(256 + grow) * H_ + k];
                } else if (k < 133) {
                    fr = w_ih[grow * DIN + (k - 128)];
                    fz = w_ih[(128 + grow) * DIN + (k - 128)];
                    fn = 0.f;
                } else if (k == 133) {
                    fr = b_ih[grow] + b_hh[grow];
                    fz = b_ih[128 + grow] + b_hh[128 + grow];
                    fn = b_hh[256 + grow];
                } else { fr = 0.f; fz = 0.f; fn = 0.f; }
                vr[j] = (_Float16)fr; vz[j] = (_Float16)fz; vn[j] = (_Float16)fn;
            }
            a_r[i][c] = vr; a_z[i][c] = vz; a_n[i][c] = vn;
        }
        half8 vx;
#pragma unroll
        for (int j = 0; j < 8; ++j) {
            const int k = 128 + g * 8 + j;   // chunk 4 only
            float f = 0.f;
            if (k < 133)       f = w_ih[(256 + grow) * DIN + (k - 128)];
            else if (k == 133) f = b_ih[256 + grow];
            vx[j] = (_Float16)f;
        }
        a_x[i] = vx;
    }

    // ---- init LDS: zero both buffers ----
#pragma unroll
    for (int q = 0; q < 4; ++q) {
        f32x4 z = {0.f, 0.f, 0.f, 0.f};
        *reinterpret_cast<f32x4*>(smem + tid * 64 + q * 16) = z;
    }
    __syncthreads();
    // constants (k=133 -> 1.0) in both buffers, and x_0 into buffer 0
    if (tid < 32) {
        const int row = tid & 15, bu = tid >> 4;
        *(_Float16*)(smem + bu * 8192 + row * 512 + (266 ^ ((row & 7) << 4))) =
            (_Float16)1.0f;
    }
    if (tid < 80) {
        const int bb = tid / 5, d = tid % 5;
        const int tt0 = dir ? (T_ - 1) : 0;
        const float xv = seq[((size_t)(bg * 16 + bb) * T_ + tt0) * DIN + d];
        *(_Float16*)(smem + bb * 512 + ((256 + 2 * d) ^ ((bb & 7) << 4))) =
            (_Float16)xv;
    }
    __syncthreads();

    float h_old[2][4];
#pragma unroll
    for (int i = 0; i < 2; ++i)
#pragma unroll
        for (int q = 0; q < 4; ++q) h_old[i][q] = 0.f;

    const bool stager = tid < 80;
    const int sb = tid / 5, sd = tid % 5;
    const size_t seqbase = (size_t)(bg * 16 + sb) * T_ * DIN + sd;

    for (int t = 0; t < T_; ++t) {
        char* cur = smem + (t & 1) * 8192;
        char* nxt = smem + ((t + 1) & 1) * 8192;

        // B fragments from LDS (h | x | 1)
        half8 bf[5];
#pragma unroll
        for (int c = 0; c < 5; ++c)
            bf[c] = *reinterpret_cast<const half8*>(
                cur + lo * 512 + ((c * 64 + g * 16) ^ ((lo & 7) << 4)));

        // issue next-step x load early (hidden under MFMA)
        float xv = 0.f;
        {
            const int t2 = (t + 1 < T_) ? t + 1 : t;
            const int tt2 = dir ? (T_ - 1 - t2) : t2;
            if (stager) xv = seq[seqbase + (size_t)tt2 * DIN];
        }

        f32x4 accr[2], accz[2], accn[2], accx[2];
#pragma unroll
        for (int i = 0; i < 2; ++i) {
            f32x4 zr = {0.f, 0.f, 0.f, 0.f};
            accr[i] = zr; accz[i] = zr; accn[i] = zr;
#pragma unroll
            for (int c = 0; c < 5; ++c) {
                accr[i] = __builtin_amdgcn_mfma_f32_16x16x32_f16(a_r[i][c], bf[c], accr[i], 0, 0, 0);
                accz[i] = __builtin_amdgcn_mfma_f32_16x16x32_f16(a_z[i][c], bf[c], accz[i], 0, 0, 0);
                accn[i] = __builtin_amdgcn_mfma_f32_16x16x32_f16(a_n[i][c], bf[c], accn[i], 0, 0, 0);
            }
            accx[i] = __builtin_amdgcn_mfma_f32_16x16x32_f16(a_x[i], bf[4], zr, 0, 0, 0);
        }

        const int tt = dir ? (T_ - 1 - t) : t;
#pragma unroll
        for (int i = 0; i < 2; ++i) {
            float hn[4];
#pragma unroll
            for (int q = 0; q < 4; ++q) {
                const float r = sigmoid_f(accr[i][q]);
                const float z = sigmoid_f(accz[i][q]);
                const float n = tanh_f(accx[i][q] + r * accn[i][q]);
                hn[q] = n + z * (h_old[i][q] - n);
                h_old[i][q] = hn[q];
            }
            const int j0 = (2 * w + i) * 16 + g * 4;
            const unsigned long long pu = pack4h(hn);
            *reinterpret_cast<unsigned long long*>(
                &y0[((size_t)(bg * 16 + lo) * T_ + tt) * D1 + dir * H_ + j0]) = pu;
            *reinterpret_cast<unsigned long long*>(
                nxt + lo * 512 + ((2 * j0) ^ ((lo & 7) << 4))) = pu;
        }
        if (stager)
            *(_Float16*)(nxt + sb * 512 + ((256 + 2 * sd) ^ ((sb & 7) << 4))) =
                (_Float16)xv;
        __syncthreads();
    }
}

// ---------------------------------------------------------------------------
// gemm1: gx = y0(f16) @ W1f^T + b, one 128-t chunk. f16 MFMA.
// grid (128 m-blocks, 6 n-blocks), 256 threads (2x2 waves, 64x32 per wave).
// ---------------------------------------------------------------------------
__global__ __launch_bounds__(256, 2) void gemm1_f16(
    const __half* __restrict__ A,   // y0h
    const float* __restrict__ W,    // 384 x 256
    const float* __restrict__ bias, // 384
    float* __restrict__ C,          // (B*CH) x 384
    int c0)
{
    __shared__ __align__(16) _Float16 As[128][32];
    __shared__ __align__(16) _Float16 Bs[64][32];
    const int tid = threadIdx.x;
    const int wave = tid >> 6, l = tid & 63;
    const int wm = wave >> 1, wn = wave & 1;
    const int lo = l & 15, g = l >> 4;
    const int m0 = blockIdx.x * 128, n0 = blockIdx.y * 64;

    f32x4 acc[4][2];
#pragma unroll
    for (int mt = 0; mt < 4; ++mt)
#pragma unroll
        for (int nt = 0; nt < 2; ++nt) {
            f32x4 z = {0.f, 0.f, 0.f, 0.f};
            acc[mt][nt] = z;
        }

    for (int kc = 0; kc < 256; kc += 32) {
#pragma unroll
        for (int r2 = 0; r2 < 2; ++r2) {
            const int idx = tid + r2 * 256;
            const int row = idx >> 2, seg = idx & 3;
            const int m = m0 + row, bb = m >> 7, tl = m & 127;
            const __half* src = A + ((size_t)bb * T_ + c0 + tl) * D1 + kc + seg * 8;
            *reinterpret_cast<uint4*>(&As[row][seg * 8]) =
                *reinterpret_cast<const uint4*>(src);
        }
        {
            const int row = tid >> 2, seg = tid & 3;
            const float* srcw = W + (size_t)(n0 + row) * D1 + kc + seg * 8;
            const float4 u0 = *reinterpret_cast<const float4*>(srcw);
            const float4 u1 = *reinterpret_cast<const float4*>(srcw + 4);
            half8 hv;
            hv[0] = (_Float16)u0.x; hv[1] = (_Float16)u0.y;
            hv[2] = (_Float16)u0.z; hv[3] = (_Float16)u0.w;
            hv[4] = (_Float16)u1.x; hv[5] = (_Float16)u1.y;
            hv[6] = (_Float16)u1.z; hv[7] = (_Float16)u1.w;
            *reinterpret_cast<half8*>(&Bs[row][seg * 8]) = hv;
        }
        __syncthreads();
        half8 af[4], bfr[2];
#pragma unroll
        for (int mt = 0; mt < 4; ++mt)
            af[mt] = *reinterpret_cast<half8*>(&As[wm * 64 + mt * 16 + lo][g * 8]);
#pragma unroll
        for (int nt = 0; nt < 2; ++nt)
            bfr[nt] = *reinterpret_cast<half8*>(&Bs[wn * 32 + nt * 16 + lo][g * 8]);
#pragma unroll
        for (int mt = 0; mt < 4; ++mt)
#pragma unroll
            for (int nt = 0; nt < 2; ++nt)
                acc[mt][nt] = __builtin_amdgcn_mfma_f32_16x16x32_f16(
                    af[mt], bfr[nt], acc[mt][nt], 0, 0, 0);
        __syncthreads();
    }
#pragma unroll
    for (int nt = 0; nt < 2; ++nt) {
        const int n = n0 + wn * 32 + nt * 16 + lo;
        const float bv = bias[n];
#pragma unroll
        for (int mt = 0; mt < 4; ++mt) {
            const int mrow = m0 + wm * 64 + mt * 16 + g * 4;
#pragma unroll
            for (int q = 0; q < 4; ++q)
                C[(size_t)(mrow + q) * G3 + n] = acc[mt][nt][q] + bv;
        }
    }
}

// ---------------------------------------------------------------------------
// scan1: layer-1 forward over one 128-t chunk, MFMA-based. 8 blocks x 256.
// gx (incl. b_ih) precomputed; b_hh added in epilogue from registers.
// K = 128 (4 chunks).  LDS stride 256B, same XOR swizzle, double-buffered.
// ---------------------------------------------------------------------------
__global__ __launch_bounds__(256, 2) void scan1_mfma(
    const float* __restrict__ gxc,   // [128 batches][CH][384]
    const float* __restrict__ whh, const float* __restrict__ bhh,
    float* __restrict__ h1, int c)
{
    const int tid = threadIdx.x;
    const int w = tid >> 6, l = tid & 63;
    const int lo = l & 15, g = l >> 4;
    const int bg = blockIdx.x;       // 0..7

    __shared__ __align__(16) char smem[2 * 16 * 256];   // 8KB

    half8 a_r[2][4], a_z[2][4], a_n[2][4];
    float br[2][4], bz[2][4], bn[2][4];
#pragma unroll
    for (int i = 0; i < 2; ++i) {
        const int grow = (2 * w + i) * 16 + lo;
#pragma unroll
        for (int cc = 0; cc < 4; ++cc) {
            half8 vr, vz, vn;
#pragma unroll
            for (int j = 0; j < 8; ++j) {
                const int k = cc * 32 + g * 8 + j;
                vr[j] = (_Float16)whh[grow * H_ + k];
                vz[j] = (_Float16)whh[(128 + grow) * H_ + k];
                vn[j] = (_Float16)whh[(256 + grow) * H_ + k];
            }
            a_r[i][cc] = vr; a_z[i][cc] = vz; a_n[i][cc] = vn;
        }
#pragma unroll
        for (int q = 0; q < 4; ++q) {
            const int gq = (2 * w + i) * 16 + g * 4 + q;
            br[i][q] = bhh[gq];
            bz[i][q] = bhh[128 + gq];
            bn[i][q] = bhh[256 + gq];
        }
    }

    // init LDS
#pragma unroll
    for (int q = 0; q < 2; ++q) {
        f32x4 z = {0.f, 0.f, 0.f, 0.f};
        *reinterpret_cast<f32x4*>(smem + tid * 32 + q * 16) = z;
    }
    __syncthreads();

    float h_old[2][4];
    if (c == 0) {
#pragma unroll
        for (int i = 0; i < 2; ++i)
#pragma unroll
            for (int q = 0; q < 4; ++q) h_old[i][q] = 0.f;
    } else {
#pragma unroll
        for (int i = 0; i < 2; ++i) {
            const int j0 = (2 * w + i) * 16 + g * 4;
            const f32x4 hv = *reinterpret_cast<const f32x4*>(
                &h1[(bg * 16 + lo) * H_ + j0]);
            float hn[4];
#pragma unroll
            for (int q = 0; q < 4; ++q) { h_old[i][q] = hv[q]; hn[q] = hv[q]; }
            *reinterpret_cast<unsigned long long*>(
                smem + lo * 256 + ((2 * j0) ^ ((lo & 7) << 4))) = pack4h(hn);
        }
    }
    __syncthreads();

    const float* gxl = gxc + (size_t)(bg * 16 + lo) * CH * G3;
    f32x4 gxcur[6], gxnxt[6];
#pragma unroll
    for (int i = 0; i < 2; ++i) {
        const int gr0 = (2 * w + i) * 16 + g * 4;
        gxcur[i]     = *reinterpret_cast<const f32x4*>(gxl + gr0);
        gxcur[2 + i] = *reinterpret_cast<const f32x4*>(gxl + 128 + gr0);
        gxcur[4 + i] = *reinterpret_cast<const f32x4*>(gxl + 256 + gr0);
    }

    for (int t = 0; t < CH; ++t) {
        char* curb = smem + (t & 1) * 4096;
        char* nxtb = smem + ((t + 1) & 1) * 4096;

        half8 bf[4];
#pragma unroll
        for (int cc = 0; cc < 4; ++cc)
            bf[cc] = *reinterpret_cast<const half8*>(
                curb + lo * 256 + ((cc * 64 + g * 16) ^ ((lo & 7) << 4)));

        // prefetch next step's gx (independent of recurrence)
        const int tn = (t + 1 < CH) ? t + 1 : t;
#pragma unroll
        for (int i = 0; i < 2; ++i) {
            const int gr0 = (2 * w + i) * 16 + g * 4;
            const float* p = gxl + (size_t)tn * G3;
            gxnxt[i]     = *reinterpret_cast<const f32x4*>(p + gr0);
            gxnxt[2 + i] = *reinterpret_cast<const f32x4*>(p + 128 + gr0);
            gxnxt[4 + i] = *reinterpret_cast<const f32x4*>(p + 256 + gr0);
        }

        f32x4 accr[2], accz[2], accn[2];
#pragma unroll
        for (int i = 0; i < 2; ++i) {
            f32x4 zr = {0.f, 0.f, 0.f, 0.f};
            accr[i] = zr; accz[i] = zr; accn[i] = zr;
#pragma unroll
            for (int cc = 0; cc < 4; ++cc) {
                accr[i] = __builtin_amdgcn_mfma_f32_16x16x32_f16(a_r[i][cc], bf[cc], accr[i], 0, 0, 0);
                accz[i] = __builtin_amdgcn_mfma_f32_16x16x32_f16(a_z[i][cc], bf[cc], accz[i], 0, 0, 0);
                accn[i] = __builtin_amdgcn_mfma_f32_16x16x32_f16(a_n[i][cc], bf[cc], accn[i], 0, 0, 0);
            }
        }

#pragma unroll
        for (int i = 0; i < 2; ++i) {
            float hn[4];
#pragma unroll
            for (int q = 0; q < 4; ++q) {
                const float r = sigmoid_f(accr[i][q] + br[i][q] + gxcur[i][q]);
                const float z = sigmoid_f(accz[i][q] + bz[i][q] + gxcur[2 + i][q]);
                const float n = tanh_f(gxcur[4 + i][q] + r * (accn[i][q] + bn[i][q]));
                hn[q] = n + z * (h_old[i][q] - n);
                h_old[i][q] = hn[q];
            }
            const int j0 = (2 * w + i) * 16 + g * 4;
            *reinterpret_cast<unsigned long long*>(
                nxtb + lo * 256 + ((2 * j0) ^ ((lo & 7) << 4))) = pack4h(hn);
        }
#pragma unroll
        for (int i = 0; i < 6; ++i) gxcur[i] = gxnxt[i];
        __syncthreads();
    }

#pragma unroll
    for (int i = 0; i < 2; ++i) {
        const int j0 = (2 * w + i) * 16 + g * 4;
        f32x4 hv;
#pragma unroll
        for (int q = 0; q < 4; ++q) hv[q] = h_old[i][q];
        *reinterpret_cast<f32x4*>(&h1[(bg * 16 + lo) * H_ + j0]) = hv;
    }
}

// ---------------------------------------------------------------------------
// Layer-1 backward single step at t=T-1 (h0=0 -> gh=b_hh) + FC head.
// ---------------------------------------------------------------------------
__global__ __launch_bounds__(384, 1) void back1_fc(
    const __half* __restrict__ y0, const float* __restrict__ h1,
    const float* __restrict__ w_ih_1b, const float* __restrict__ b_ih_1b,
    const float* __restrict__ b_hh_1b,
    const float* __restrict__ fc_w, const float* __restrict__ fc_b,
    float* __restrict__ out)
{
    const int g = threadIdx.x;
    const int b = blockIdx.x;
    __shared__ float ylast[D1];
    __shared__ float pre_rz[2 * H_];
    __shared__ float gxn[H_], ghn[H_];
    __shared__ float hb[H_];
    __shared__ float red[H_];

    if (g < D1) ylast[g] = __half2float(y0[((size_t)b * T_ + (T_ - 1)) * D1 + g]);
    __syncthreads();

    float accb = b_ih_1b[g];
    const float* wrow = w_ih_1b + (size_t)g * D1;
#pragma unroll 8
    for (int k = 0; k < D1; k += 4) {
        const float4 v = *reinterpret_cast<const float4*>(&ylast[k]);
        const float4 wv = *reinterpret_cast<const float4*>(&wrow[k]);
        accb += v.x * wv.x + v.y * wv.y + v.z * wv.z + v.w * wv.w;
    }
    const float bh2 = b_hh_1b[g];
    if (g < 2 * H_) pre_rz[g] = accb + bh2;
    else            { gxn[g - 2 * H_] = accb; ghn[g - 2 * H_] = bh2; }
    __syncthreads();
    if (g < H_) {
        const float r = sigmoid_f(pre_rz[g]);
        const float z = sigmoid_f(pre_rz[g + H_]);
        const float n = tanh_f(gxn[g] + r * ghn[g]);
        hb[g] = (1.0f - z) * n;
    }
    __syncthreads();
    if (g < H_) red[g] = h1[b * H_ + g] * fc_w[g] + hb[g] * fc_w[H_ + g];
    __syncthreads();
    if (g == 0) {
        float s = fc_b[0];
#pragma unroll 8
        for (int k = 0; k < H_; ++k) s += red[k];
        out[b] = s;
    }
}

// ---------------------------------------------------------------------------
extern "C" void kernel_launch(void* const* d_in, const int* in_sizes, int n_in,
                              void* d_out, int out_size, void* d_ws, size_t ws_size,
                              hipStream_t stream)
{
    const float* seq      = (const float*)d_in[0];
    const float* w_ih_l0f = (const float*)d_in[1];
    const float* w_hh_l0f = (const float*)d_in[2];
    const float* b_ih_l0f = (const float*)d_in[3];
    const float* b_hh_l0f = (const float*)d_in[4];
    const float* w_ih_l0b = (const float*)d_in[5];
    const float* w_hh_l0b = (const float*)d_in[6];
    const float* b_ih_l0b = (const float*)d_in[7];
    const float* b_hh_l0b = (const float*)d_in[8];
    const float* w_ih_l1f = (const float*)d_in[9];
    const float* w_hh_l1f = (const float*)d_in[10];
    const float* b_ih_l1f = (const float*)d_in[11];
    const float* b_hh_l1f = (const float*)d_in[12];
    const float* w_ih_l1b = (const float*)d_in[13];
    // d_in[14] = w_hh_l1b unused: only t=T-1 of the reversed layer-1 backward
    // is needed, and there h0=0 -> gh = b_hh_l1b.
    const float* b_ih_l1b = (const float*)d_in[15];
    const float* b_hh_l1b = (const float*)d_in[16];
    const float* fc_w     = (const float*)d_in[17];
    const float* fc_b     = (const float*)d_in[18];
    float* out = (float*)d_out;

    __half* y0h = (__half*)d_ws;                          // 128 MiB
    float*  gxc = (float*)((char*)d_ws +
                  (size_t)B_ * T_ * D1 * sizeof(__half)); // 24 MiB
    float*  h1  = gxc + (size_t)B_ * CH * G3;             // 64 KiB

    hipLaunchKernelGGL(scan0_mfma, dim3(16), dim3(256), 0, stream,
        seq, w_ih_l0f, w_hh_l0f, b_ih_l0f, b_hh_l0f,
             w_ih_l0b, w_hh_l0b, b_ih_l0b, b_hh_l0b, y0h);

    for (int ci = 0; ci < NCH; ++ci) {
        hipLaunchKernelGGL(gemm1_f16, dim3(128, 6), dim3(256), 0, stream,
            y0h, w_ih_l1f, b_ih_l1f, gxc, ci * CH);
        hipLaunchKernelGGL(scan1_mfma, dim3(8), dim3(256), 0, stream,
            gxc, w_hh_l1f, b_hh_l1f, h1, ci);
    }

    hipLaunchKernelGGL(back1_fc, dim3(B_), dim3(384), 0, stream,
        y0h, h1, w_ih_l1b, b_ih_l1b, b_hh_l1b, fc_w, fc_b, out);
}